// Round 1
// baseline (5989.130 us; speedup 1.0000x reference)
//
#include <hip/hip_runtime.h>
#include <math.h>

#define L_ 24
#define D_ 1024
#define H_ 16
#define HD_ 64
#define S_ 4096
#define NPI_ 32
#define NV_ 7
#define NC_ 8

#define ABLK 512            // attention blocks (x256 thr) -> G waves
#define G_ (ABLK*4)         // 2048 attention waves
#define MV_CH 16            // rows per matvec i-chunk
#define MV_NB (D_/MV_CH)    // 64 blocks per matrix

// ws layout (floats)
#define ACC_OFF   0                       // L*6*D accumulators (q,k,v,y1,h,y2)
#define VALS_OFF  (L_*6*D_)
#define MPART_OFF (VALS_OFF + D_)
#define LPART_OFF (MPART_OFF + G_*H_)
#define OPART_OFF (LPART_OFF + G_*H_)     // G_*D_ floats

// ---- block-wide mean/var of a 1024-float vector (blockDim=256) ----
__device__ __forceinline__ void block_meanvar(const float* __restrict__ v,
                                              float* red, float* red2,
                                              float& mean, float& rsig) {
  int tid = threadIdx.x;
  float4 a = ((const float4*)v)[tid];
  red[tid]  = a.x + a.y + a.z + a.w;
  red2[tid] = a.x*a.x + a.y*a.y + a.z*a.z + a.w*a.w;
  __syncthreads();
  for (int off = 128; off > 0; off >>= 1) {
    if (tid < off) { red[tid] += red[tid+off]; red2[tid] += red2[tid+off]; }
    __syncthreads();
  }
  float m = red[0] * (1.0f/D_);
  float var = red2[0] * (1.0f/D_) - m*m;
  mean = m;
  rsig = rsqrtf(var + 1e-6f);
  __syncthreads();   // allow red/red2 reuse
}

// ---- QKV matvec: acc{q,k,v} += LN(P) @ W  (+bias from i-chunk 0) ----
__global__ __launch_bounds__(256) void k_qkv(
    const float* __restrict__ P, const float* __restrict__ lnS, const float* __restrict__ lnB,
    const float* __restrict__ Wq, const float* __restrict__ bq,
    const float* __restrict__ Wk, const float* __restrict__ bk,
    const float* __restrict__ Wv, const float* __restrict__ bv,
    float* __restrict__ accq, float* __restrict__ acck, float* __restrict__ accv)
{
  __shared__ float red[256], red2[256];
  __shared__ float sxn[MV_CH];
  int tid = threadIdx.x;
  float mean = 0.f, rsig = 0.f;
  if (lnS) block_meanvar(P, red, red2, mean, rsig);
  int i0 = blockIdx.x * MV_CH;
  if (tid < MV_CH) {
    float xv = P[i0 + tid];
    sxn[tid] = lnS ? ((xv - mean) * rsig * lnS[i0+tid] + lnB[i0+tid]) : xv;
  }
  __syncthreads();
  const float* W; const float* b; float* acc;
  if (blockIdx.y == 0)      { W = Wq; b = bq; acc = accq; }
  else if (blockIdx.y == 1) { W = Wk; b = bk; acc = acck; }
  else                      { W = Wv; b = bv; acc = accv; }
  float4 a = {0.f,0.f,0.f,0.f};
  const float4* Wr = (const float4*)(W + (size_t)i0 * D_);
  #pragma unroll
  for (int ii = 0; ii < MV_CH; ++ii) {
    float4 w = Wr[ii*(D_/4) + tid];
    float xv = sxn[ii];
    a.x += xv*w.x; a.y += xv*w.y; a.z += xv*w.z; a.w += xv*w.w;
  }
  if (blockIdx.x == 0) {
    float4 bb = ((const float4*)b)[tid];
    a.x += bb.x; a.y += bb.y; a.z += bb.z; a.w += bb.w;
  }
  atomicAdd(&acc[tid*4+0], a.x);
  atomicAdd(&acc[tid*4+1], a.y);
  atomicAdd(&acc[tid*4+2], a.z);
  atomicAdd(&acc[tid*4+3], a.w);
}

// ---- generic matvec: acc += f(vin) @ W (+ bias + optional residual, chunk 0) ----
// vin_mode: 0 raw, 1 relu, 2 layernorm(lnS,lnB)
// res_mode: 0 none, 1 add LN(resP; rS,rB) (identity if rS==null)
__global__ __launch_bounds__(256) void k_mv(
    const float* __restrict__ W, const float* __restrict__ bias,
    const float* __restrict__ vin, int vin_mode,
    const float* __restrict__ lnS, const float* __restrict__ lnB,
    const float* __restrict__ resP, int res_mode,
    const float* __restrict__ rS, const float* __restrict__ rB,
    float* __restrict__ acc)
{
  __shared__ float red[256], red2[256];
  __shared__ float sxn[MV_CH];
  int tid = threadIdx.x;
  int i0 = blockIdx.x * MV_CH;
  if (vin_mode == 2) {
    float mean, rsig;
    block_meanvar(vin, red, red2, mean, rsig);
    if (tid < MV_CH) {
      float xv = vin[i0 + tid];
      sxn[tid] = (xv - mean) * rsig * lnS[i0+tid] + lnB[i0+tid];
    }
  } else if (tid < MV_CH) {
    float xv = vin[i0 + tid];
    sxn[tid] = (vin_mode == 1) ? fmaxf(xv, 0.f) : xv;
  }
  __syncthreads();
  float4 a = {0.f,0.f,0.f,0.f};
  const float4* Wr = (const float4*)(W + (size_t)i0 * D_);
  #pragma unroll
  for (int ii = 0; ii < MV_CH; ++ii) {
    float4 w = Wr[ii*(D_/4) + tid];
    float xv = sxn[ii];
    a.x += xv*w.x; a.y += xv*w.y; a.z += xv*w.z; a.w += xv*w.w;
  }
  if (blockIdx.x == 0) {
    float4 bb = ((const float4*)bias)[tid];
    a.x += bb.x; a.y += bb.y; a.z += bb.z; a.w += bb.w;
    if (res_mode) {
      float4 r;
      float4 p = ((const float4*)resP)[tid];
      if (rS) {
        float mean2, rsig2;
        block_meanvar(resP, red, red2, mean2, rsig2);
        float4 s4 = ((const float4*)rS)[tid];
        float4 b4 = ((const float4*)rB)[tid];
        r.x = (p.x-mean2)*rsig2*s4.x + b4.x;
        r.y = (p.y-mean2)*rsig2*s4.y + b4.y;
        r.z = (p.z-mean2)*rsig2*s4.z + b4.z;
        r.w = (p.w-mean2)*rsig2*s4.w + b4.w;
      } else {
        r = p;
      }
      a.x += r.x; a.y += r.y; a.z += r.z; a.w += r.w;
    }
  }
  atomicAdd(&acc[tid*4+0], a.x);
  atomicAdd(&acc[tid*4+1], a.y);
  atomicAdd(&acc[tid*4+2], a.z);
  atomicAdd(&acc[tid*4+3], a.w);
}

// ---- fused cache-shift + attention partials ----
// one wave = full 16 heads for its positions; lane owns 16 floats of each row
__global__ __launch_bounds__(256) void k_attn(
    const float* __restrict__ cache_l,   // cache + l*2*S*D
    float* __restrict__ outc_l,          // d_out cache region + l*2*S*D
    const float* __restrict__ accq, const float* __restrict__ bq,
    float* __restrict__ mpart, float* __restrict__ lpart, float* __restrict__ opart)
{
  int tid = threadIdx.x;
  int lane = tid & 63;
  int g = blockIdx.x * 4 + (tid >> 6);

  float q[16];
  {
    const float4* qa = (const float4*)(accq + lane*16);
    const float4* qb = (const float4*)(bq + lane*16);
    #pragma unroll
    for (int i = 0; i < 4; ++i) {
      float4 a = qa[i], b = qb[i];
      q[i*4+0] = a.x + b.x; q[i*4+1] = a.y + b.y;
      q[i*4+2] = a.z + b.z; q[i*4+3] = a.w + b.w;
    }
  }
  float m = -INFINITY, lsum = 0.f;
  float o[16];
  #pragma unroll
  for (int i = 0; i < 16; ++i) o[i] = 0.f;

  for (int t = 0; t < 2; ++t) {
    int s = 1 + g + t * G_;
    if (s >= S_) break;
    const float4* vrow = (const float4*)(cache_l + (size_t)s * D_ + lane*16);
    const float4* krow = (const float4*)(cache_l + (size_t)(S_ + s) * D_ + lane*16);
    float4* vdst = (float4*)(outc_l + (size_t)(s-1) * D_ + lane*16);
    float4* kdst = (float4*)(outc_l + (size_t)(S_ + s - 1) * D_ + lane*16);
    float4 v4[4], k4[4];
    #pragma unroll
    for (int i = 0; i < 4; ++i) { v4[i] = vrow[i]; k4[i] = krow[i]; }
    #pragma unroll
    for (int i = 0; i < 4; ++i) { vdst[i] = v4[i]; kdst[i] = k4[i]; }
    float v[16], k[16];
    #pragma unroll
    for (int i = 0; i < 4; ++i) {
      v[i*4+0]=v4[i].x; v[i*4+1]=v4[i].y; v[i*4+2]=v4[i].z; v[i*4+3]=v4[i].w;
      k[i*4+0]=k4[i].x; k[i*4+1]=k4[i].y; k[i*4+2]=k4[i].z; k[i*4+3]=k4[i].w;
    }
    bool nz = false;
    #pragma unroll
    for (int i = 0; i < 16; ++i) nz |= (v[i] != 0.f);
    int anyv = __any((int)nz);
    float dot = 0.f;
    #pragma unroll
    for (int i = 0; i < 16; ++i) dot += q[i] * k[i];
    dot += __shfl_xor(dot, 1);
    dot += __shfl_xor(dot, 2);
    float logit = anyv ? dot * 0.125f : -INFINITY;
    float mnew = fmaxf(m, logit);
    if (mnew != -INFINITY) {
      float alpha = (m == -INFINITY) ? 0.f : __expf(m - mnew);
      float p = (logit == -INFINITY) ? 0.f : __expf(logit - mnew);
      lsum = lsum * alpha + p;
      #pragma unroll
      for (int i = 0; i < 16; ++i) o[i] = o[i] * alpha + p * v[i];
      m = mnew;
    }
  }
  int h = lane >> 2;
  if ((lane & 3) == 0) { mpart[g*H_ + h] = m; lpart[g*H_ + h] = lsum; }
  float4* od = (float4*)(opart + (size_t)g * D_ + lane*16);
  #pragma unroll
  for (int i = 0; i < 4; ++i) {
    float4 t4; t4.x = o[i*4+0]; t4.y = o[i*4+1]; t4.z = o[i*4+2]; t4.w = o[i*4+3];
    od[i] = t4;
  }
}

// ---- combine partials per head + new-token term -> vals; write cache row S-1 ----
__global__ __launch_bounds__(256) void k_red(
    const float* __restrict__ accq, const float* __restrict__ bq,
    const float* __restrict__ acck, const float* __restrict__ bk,
    const float* __restrict__ accv, const float* __restrict__ bv,
    const float* __restrict__ mpart, const float* __restrict__ lpart,
    const float* __restrict__ opart,
    float* __restrict__ vals, float* __restrict__ outc_l)
{
  int h = blockIdx.x, tid = threadIdx.x;
  __shared__ float swg[G_];
  __shared__ float red[256];
  __shared__ float sO[256];
  __shared__ float sq[HD_], ski[HD_], svi[HD_];
  __shared__ int sflag;
  if (tid == 0) sflag = 0;
  if (tid < HD_) {
    int j = h*HD_ + tid;
    sq[tid]  = accq[j] + bq[j];
    ski[tid] = acck[j] + bk[j];
    svi[tid] = accv[j] + bv[j];
  }
  __syncthreads();
  // mask over full v_i
  bool nz = false;
  for (int j = tid; j < D_; j += 256) nz |= ((accv[j] + bv[j]) != 0.f);
  if (nz) atomicOr(&sflag, 1);
  // new-token logit: dot(q_h, k_i_h)
  float dp = (tid < HD_) ? sq[tid] * ski[tid] : 0.f;
  red[tid] = dp;
  __syncthreads();
  for (int off = 128; off > 0; off >>= 1) {
    if (tid < off) red[tid] += red[tid+off];
    __syncthreads();
  }
  float logitN = red[0] * 0.125f;
  int maskN = sflag;
  __syncthreads();
  // global max M
  float lm = maskN ? logitN : -INFINITY;
  for (int g = tid; g < G_; g += 256) lm = fmaxf(lm, mpart[g*H_ + h]);
  red[tid] = lm;
  __syncthreads();
  for (int off = 128; off > 0; off >>= 1) {
    if (tid < off) red[tid] = fmaxf(red[tid], red[tid+off]);
    __syncthreads();
  }
  float M = red[0];
  __syncthreads();
  // weights + L
  float ll = 0.f;
  for (int g = tid; g < G_; g += 256) {
    float mg = mpart[g*H_ + h];
    float w = (mg == -INFINITY) ? 0.f : __expf(mg - M);
    swg[g] = w;
    ll += w * lpart[g*H_ + h];
  }
  red[tid] = ll;
  __syncthreads();
  for (int off = 128; off > 0; off >>= 1) {
    if (tid < off) red[tid] += red[tid+off];
    __syncthreads();
  }
  float pN = maskN ? __expf(logitN - M) : 0.f;
  float Lsum = red[0] + pN;
  __syncthreads();
  // O accumulation: d = tid&63, 4 g-slices
  int d = tid & 63, slice = tid >> 6;
  float so = 0.f;
  for (int g = slice * (G_/4); g < (slice+1) * (G_/4); ++g)
    so += swg[g] * opart[(size_t)g * D_ + h*HD_ + d];
  sO[tid] = so;
  __syncthreads();
  if (tid < HD_) {
    float O = sO[tid] + sO[tid+64] + sO[tid+128] + sO[tid+192] + pN * svi[tid];
    vals[h*HD_ + tid] = O / Lsum;
    outc_l[(size_t)(S_-1) * D_ + h*HD_ + tid]   = svi[tid];  // v plane row S-1
    outc_l[(size_t)(2*S_-1) * D_ + h*HD_ + tid] = ski[tid];  // k plane row S-1
  }
}

// ---- final: x_out = LN2_23(y2); head logits ----
__global__ __launch_bounds__(256) void k_heads(
    const float* __restrict__ y2, const float* __restrict__ lnS, const float* __restrict__ lnB,
    const float* __restrict__ Wpi, const float* __restrict__ bpi,
    const float* __restrict__ Wvh, const float* __restrict__ bvh,
    const float* __restrict__ Wc,  const float* __restrict__ bc,
    float* __restrict__ out)
{
  __shared__ float red[256], red2[256];
  int tid = threadIdx.x;
  float mean, rsig;
  block_meanvar(y2, red, red2, mean, rsig);
  if (blockIdx.x == 0) {
    float4 p = ((const float4*)y2)[tid];
    float4 s4 = ((const float4*)lnS)[tid];
    float4 b4 = ((const float4*)lnB)[tid];
    float4 r;
    r.x = (p.x-mean)*rsig*s4.x + b4.x;
    r.y = (p.y-mean)*rsig*s4.y + b4.y;
    r.z = (p.z-mean)*rsig*s4.z + b4.z;
    r.w = (p.w-mean)*rsig*s4.w + b4.w;
    ((float4*)out)[tid] = r;
  } else {
    int p = blockIdx.x - 1;
    const float* W; const float* b; int N; int col;
    if (p < NPI_)            { W = Wpi; b = bpi; N = NPI_; col = p; }
    else if (p < NPI_+NV_)   { W = Wvh; b = bvh; N = NV_;  col = p - NPI_; }
    else                     { W = Wc;  b = bc;  N = NC_;  col = p - NPI_ - NV_; }
    float acc = 0.f;
    for (int i = tid; i < D_; i += 256) {
      float xn = (y2[i]-mean)*rsig*lnS[i] + lnB[i];
      acc += xn * W[(size_t)i*N + col];
    }
    red[tid] = acc;
    __syncthreads();
    for (int off = 128; off > 0; off >>= 1) {
      if (tid < off) red[tid] += red[tid+off];
      __syncthreads();
    }
    if (tid == 0) out[D_ + p] = red[0] + b[col];
  }
}

extern "C" void kernel_launch(void* const* d_in, const int* in_sizes, int n_in,
                              void* d_out, int out_size, void* d_ws, size_t ws_size,
                              hipStream_t stream) {
  const float* x    = (const float*)d_in[0];
  const float* cache= (const float*)d_in[1];
  const float* Wv   = (const float*)d_in[2];  const float* bv  = (const float*)d_in[3];
  const float* Wq   = (const float*)d_in[4];  const float* bq  = (const float*)d_in[5];
  const float* Wk   = (const float*)d_in[6];  const float* bk  = (const float*)d_in[7];
  const float* Wo   = (const float*)d_in[8];  const float* bo  = (const float*)d_in[9];
  const float* l1s  = (const float*)d_in[10]; const float* l1b = (const float*)d_in[11];
  const float* l2s  = (const float*)d_in[12]; const float* l2b = (const float*)d_in[13];
  const float* Wf1  = (const float*)d_in[14]; const float* bf1 = (const float*)d_in[15];
  const float* Wf2  = (const float*)d_in[16]; const float* bf2 = (const float*)d_in[17];
  const float* Wpi  = (const float*)d_in[18]; const float* bpi = (const float*)d_in[19];
  const float* Wvh  = (const float*)d_in[20]; const float* bvh = (const float*)d_in[21];
  const float* Wc   = (const float*)d_in[22]; const float* bc  = (const float*)d_in[23];
  float* out = (float*)d_out;
  float* ws  = (float*)d_ws;
  float* outcache = out + D_ + NPI_ + NV_ + NC_;

  hipMemsetAsync(ws, 0, (size_t)L_*6*D_*sizeof(float), stream);

  float* vals  = ws + VALS_OFF;
  float* mpart = ws + MPART_OFF;
  float* lpart = ws + LPART_OFF;
  float* opart = ws + OPART_OFF;

  for (int l = 0; l < L_; ++l) {
    float* accq  = ws + (size_t)(l*6+0)*D_;
    float* acck  = ws + (size_t)(l*6+1)*D_;
    float* accv  = ws + (size_t)(l*6+2)*D_;
    float* accy1 = ws + (size_t)(l*6+3)*D_;
    float* acch  = ws + (size_t)(l*6+4)*D_;
    float* accy2 = ws + (size_t)(l*6+5)*D_;
    const float* P  = (l == 0) ? x : (ws + (size_t)((l-1)*6+5)*D_);
    const float* pS = (l == 0) ? nullptr : (l2s + (size_t)(l-1)*D_);
    const float* pB = (l == 0) ? nullptr : (l2b + (size_t)(l-1)*D_);
    size_t wOff = (size_t)l * D_ * D_;
    const float* cache_l = cache + (size_t)l * 2 * S_ * D_;
    float* outc_l = outcache + (size_t)l * 2 * S_ * D_;

    k_qkv<<<dim3(MV_NB,3), 256, 0, stream>>>(P, pS, pB,
        Wq+wOff, bq+(size_t)l*D_, Wk+wOff, bk+(size_t)l*D_, Wv+wOff, bv+(size_t)l*D_,
        accq, acck, accv);
    k_attn<<<ABLK, 256, 0, stream>>>(cache_l, outc_l, accq, bq+(size_t)l*D_,
        mpart, lpart, opart);
    k_red<<<H_, 256, 0, stream>>>(accq, bq+(size_t)l*D_, acck, bk+(size_t)l*D_,
        accv, bv+(size_t)l*D_, mpart, lpart, opart, vals, outc_l);
    k_mv<<<MV_NB, 256, 0, stream>>>(Wo+wOff, bo+(size_t)l*D_, vals, 0, nullptr, nullptr,
        P, 1, pS, pB, accy1);
    k_mv<<<MV_NB, 256, 0, stream>>>(Wf1+wOff, bf1+(size_t)l*D_, accy1, 2,
        l1s+(size_t)l*D_, l1b+(size_t)l*D_, nullptr, 0, nullptr, nullptr, acch);
    k_mv<<<MV_NB, 256, 0, stream>>>(Wf2+wOff, bf2+(size_t)l*D_, acch, 1, nullptr, nullptr,
        accy1, 1, l1s+(size_t)l*D_, l1b+(size_t)l*D_, accy2);
  }
  k_heads<<<1+NPI_+NV_+NC_, 256, 0, stream>>>(
      ws + (size_t)(23*6+5)*D_, l2s + (size_t)23*D_, l2b + (size_t)23*D_,
      Wpi, bpi, Wvh, bvh, Wc, bc, out);
}